// Round 1
// 1454.312 us; speedup vs baseline: 1.1960x; 1.1960x over previous
//
#include <hip/hip_runtime.h>
#include <hip/hip_bf16.h>

// Problem constants
#define Hh    100
#define Ww    152
#define Pp    15200        // H*W
#define Cc    256
#define NBATCH 8
#define NC1   81
#define NCLS  80
#define KTOP  100

// padded x-tensor geometry (pixel-major bf16 hi/lo)
#define PROWS 102          // rows -1..100
#define PCOLS 154          // cols -1..152
#define PIXB  1024         // bytes per padded pixel: 256 hi + 256 lo bf16
#define XT_BATCH_BYTES ((size_t)PROWS * PCOLS * PIXB)   // 16,084,992

typedef __attribute__((ext_vector_type(8))) short  bf16x8;
typedef __attribute__((ext_vector_type(4))) float  f32x4;

__device__ __forceinline__ unsigned short bf16_bits(float v) {
    __hip_bfloat16 h = __float2bfloat16(v);
    return *(unsigned short*)&h;
}
__device__ __forceinline__ float bf16_back(float v) {
    __hip_bfloat16 h = __float2bfloat16(v);
    return __bfloat162float(h);
}

typedef __attribute__((address_space(1))) const void GV;
typedef __attribute__((address_space(3))) void LV;
__device__ __forceinline__ void gload_lds16(const void* g, void* l) {
    __builtin_amdgcn_global_load_lds((GV*)g, (LV*)l, 16, 0, 0);
}

// ---------------------------------------------------------------------------
// Kernel 0a: pack w1 (OIHW fp32) into A-fragment order, bf16 hi/lo.
// Region r = ((s*9+t)*2+prec): 16 M-tiles x 64 lanes x 8 bf16 = 8192 shorts.
// Within region: mt=k>>4; lane=quad(c)*16 + (k&15); j=c&7.
// ---------------------------------------------------------------------------
__global__ void pack_w(const float* __restrict__ w1, unsigned short* __restrict__ wpk)
{
    int id = blockIdx.x * 256 + threadIdx.x;    // 0..65535
    int k = id >> 8, c = id & 255;
#pragma unroll
    for (int t = 0; t < 9; ++t) {
        float v = w1[(size_t)(k * 256 + c) * 9 + t];
        unsigned short hi = bf16_bits(v);
        unsigned short lo = bf16_bits(v - bf16_back(v));
        int region = ((c >> 5) * 9 + t) * 2;
        int base   = region * 8192;
        int pos    = (k >> 4) * 512 + ((c >> 3) & 3) * 128 + (k & 15) * 8 + (c & 7);
        wpk[base + pos]        = hi;
        wpk[base + 8192 + pos] = lo;
    }
}

// ---------------------------------------------------------------------------
// Kernel 0b: pack x into zero-padded pixel-major bf16 hi/lo:
// xT[n][row 0..101][col 0..153][256 hi | 256 lo]. Borders = 0.
// ---------------------------------------------------------------------------
__global__ void pack_x(const float* __restrict__ x, unsigned short* __restrict__ xT)
{
    int col = threadIdx.x;          // 0..255, active < PCOLS
    int row = blockIdx.x;           // 0..101
    int c   = blockIdx.y;           // 0..255
    int n   = blockIdx.z;
    if (col >= PCOLS) return;
    int yy = row - 1, xx = col - 1;
    float v = 0.f;
    if ((unsigned)yy < (unsigned)Hh && (unsigned)xx < (unsigned)Ww)
        v = x[((size_t)(n * Cc + c)) * Pp + yy * Ww + xx];
    unsigned short hi = bf16_bits(v);
    unsigned short lo = bf16_bits(v - bf16_back(v));
    size_t dst = (((size_t)n * PROWS + row) * PCOLS + col) * 512 + c;
    xT[dst]       = hi;
    xT[dst + 256] = lo;
}

// ---------------------------------------------------------------------------
// Kernel 1: 3x3 conv (SAME) + bias + ReLU via MFMA bf16x3 split.
// LDS-staged rewrite:
//   Block: 512 thr = 8 waves (2 wm x 4 wn). Out 128 ch x (8 rows x 32 cols).
//   B: per s, halo window 10x34 px x [32ch hi|32ch lo] = 128 B/px, XOR-swizzled
//      (slot ^= pix&7), double-buffered (2 x 48 KB), staged via global_load_lds
//      with inverse-swizzled per-lane global source.
//   A: per (s,t), 16 KB fragment slice, TRIPLE-buffered (3 x 16 KB); counted
//      vmcnt(8/2) at tap end (never 0 in steady state) + one s_barrier/tap.
//   Frag reads are ds_read_b128 (conflict-free); 48 MFMAs/tap/wave, setprio.
// LDS total: 48K (A) + 96K (B) = 144 KB -> 1 block/CU, 2 waves/SIMD.
// ---------------------------------------------------------------------------
#define AOFF  0
#define BOFF  49152
#define BBUFB 49152

__global__ __launch_bounds__(512, 2)
void conv3x3_mfma(const unsigned short* __restrict__ xT,
                  const unsigned short* __restrict__ wpk,
                  const float* __restrict__ b1, float* __restrict__ hid)
{
    __shared__ f32x4 ldsbuf[9216];           // 147,456 B
    char* L = (char*)ldsbuf;

    const int tid  = threadIdx.x;
    const int lane = tid & 63;
    const int wv   = tid >> 6;               // 0..7
    const int wm   = wv >> 2;                // 0..1
    const int wn   = wv & 3;                 // 0..3
    const int quad = lane >> 4, lq = lane & 15;

    const int bx = blockIdx.x;               // 0..64  (13 row-blocks x 5 col-blocks)
    const int rb = bx / 5, cb = bx - rb * 5;
    const int y0 = rb * 8;                   // first output row of tile
    const int x0 = cb * 32;                  // first output col of tile
    const int k0 = blockIdx.y * 128;
    const int n  = blockIdx.z;

    const char* xb = (const char*)xT + (size_t)n * XT_BATCH_BYTES;
    const char* wb = (const char*)wpk;
    const size_t kbase = (size_t)(k0 >> 4) * 1024;

    // per-lane staging constants
    const unsigned kslot = (lane & 7) ^ (lane >> 3);    // inverse-swizzle slot
    const size_t chnbase = (kslot < 4) ? (size_t)(kslot * 16)
                                       : (size_t)(448 + kslot * 16); // 512+(k-4)*16

    // ---------------- prologue: stage B(0), A(0), A(1) ----------------
    {
        // B(0) -> bbuf0  (48 instrs, 6 per wave)
#pragma unroll
        for (int k6 = 0; k6 < 6; ++k6) {
            const int j   = wv + 8 * k6;                 // 0..47
            const int pix = 8 * j + (lane >> 3);         // 0..383
            const int r   = pix / 34;
            const int c   = pix - r * 34;
            int prow = y0 + r; prow = prow < 102 ? prow : 101;
            const char* g = xb + (((size_t)(prow * 154 + x0 + c)) << 10) + chnbase;
            gload_lds16(g, L + BOFF + (size_t)j * 1024);
        }
        // A(0)->abuf0, A(1)->abuf1  (2 instrs per wave each)
#pragma unroll
        for (int uu = 0; uu < 2; ++uu) {
            const char* src = wb + (size_t)uu * 32768 + kbase
                            + (size_t)wv * 1024 + (size_t)lane * 16;
            char* dst = L + AOFF + (size_t)uu * 16384 + (size_t)wv * 1024;
            gload_lds16(src, dst);                       // hi
            gload_lds16(src + 16384, dst + 8192);        // lo
        }
        asm volatile("s_waitcnt vmcnt(0)" ::: "memory");
        __builtin_amdgcn_s_barrier();
    }

    f32x4 acc[4][4];
#pragma unroll
    for (int a = 0; a < 4; ++a)
#pragma unroll
        for (int b = 0; b < 4; ++b) acc[a][b] = 0;

    int s = 0, t = 0, cu = 0;                // cu = u % 3 (current A buf)
#pragma unroll 1
    for (int u = 0; u < 72; ++u) {
        // ---- issue A-stage for u+2 (into abuf[(cu+2)%3]) ----
        if (u < 70) {
            const int cu2 = (cu + 2 >= 3) ? (cu - 1) : (cu + 2);
            const char* src = wb + (size_t)(u + 2) * 32768 + kbase
                            + (size_t)wv * 1024 + (size_t)lane * 16;
            char* dst = L + AOFF + (size_t)cu2 * 16384 + (size_t)wv * 1024;
            gload_lds16(src, dst);
            gload_lds16(src + 16384, dst + 8192);
        }
        // ---- issue B-stage for s+1 at tap 0 ----
        if (t == 0 && s < 7) {
            const int sb = s + 1;
            char* bdst = L + BOFF + (size_t)(sb & 1) * BBUFB;
            const size_t chn = (size_t)sb * 64 + chnbase;
#pragma unroll
            for (int k6 = 0; k6 < 6; ++k6) {
                const int j   = wv + 8 * k6;
                const int pix = 8 * j + (lane >> 3);
                const int r   = pix / 34;
                const int c   = pix - r * 34;
                int prow = y0 + r; prow = prow < 102 ? prow : 101;
                const char* g = xb + (((size_t)(prow * 154 + x0 + c)) << 10) + chn;
                gload_lds16(g, bdst + (size_t)j * 1024);
            }
        }

        // ---- fragment loads from LDS ----
        {
            const char* Ab = L + AOFF + (size_t)cu * 16384;
            const char* Bb = L + BOFF + (size_t)(s & 1) * BBUFB;
            const int ty = t / 3, tx = t - ty * 3;
            const int pb0 = (wn * 2 + ty) * 34 + lq + tx;

            bf16x8 bh[4], bl[4], ah[4], al[4];
#pragma unroll
            for (int i = 0; i < 4; ++i) {
                const int pix = pb0 + (i >> 1) * 34 + (i & 1) * 16;
                const int a = pix * 128 + ((quad ^ (pix & 7)) << 4);
                bh[i] = *(const bf16x8*)(Bb + a);
                bl[i] = *(const bf16x8*)(Bb + (a ^ 64));
            }
#pragma unroll
            for (int m = 0; m < 4; ++m) {
                const char* p = Ab + (size_t)((wm * 4 + m)) * 1024 + (size_t)lane * 16;
                ah[m] = *(const bf16x8*)(p);
                al[m] = *(const bf16x8*)(p + 8192);
            }

            __builtin_amdgcn_s_setprio(1);
            // pass 1: hi*hi
#pragma unroll
            for (int m = 0; m < 4; ++m)
#pragma unroll
                for (int i = 0; i < 4; ++i)
                    acc[m][i] = __builtin_amdgcn_mfma_f32_16x16x32_bf16(ah[m], bh[i], acc[m][i], 0, 0, 0);
            // pass 2: hi*lo
#pragma unroll
            for (int m = 0; m < 4; ++m)
#pragma unroll
                for (int i = 0; i < 4; ++i)
                    acc[m][i] = __builtin_amdgcn_mfma_f32_16x16x32_bf16(ah[m], bl[i], acc[m][i], 0, 0, 0);
            // pass 3: lo*hi
#pragma unroll
            for (int m = 0; m < 4; ++m)
#pragma unroll
                for (int i = 0; i < 4; ++i)
                    acc[m][i] = __builtin_amdgcn_mfma_f32_16x16x32_bf16(al[m], bh[i], acc[m][i], 0, 0, 0);
            __builtin_amdgcn_s_setprio(0);
        }

        // ---- counted wait (guarantee A(u+1) landed; keep B in flight) ----
        if (s < 7 && t < 2)      asm volatile("s_waitcnt vmcnt(8)" ::: "memory");
        else if (u < 70)         asm volatile("s_waitcnt vmcnt(2)" ::: "memory");
        else                     asm volatile("s_waitcnt vmcnt(0)" ::: "memory");
        __builtin_amdgcn_s_barrier();

        if (++t == 9) { t = 0; ++s; }
        cu = (cu + 1 == 3) ? 0 : cu + 1;
    }

    // epilogue: bias + relu; D row = quad*4 + reg
#pragma unroll
    for (int m = 0; m < 4; ++m) {
        const int kb = k0 + wm * 64 + m * 16 + quad * 4;
        const float b0 = b1[kb], b1v = b1[kb + 1], b2v = b1[kb + 2], b3v = b1[kb + 3];
#pragma unroll
        for (int i = 0; i < 4; ++i) {
            const int y = y0 + wn * 2 + (i >> 1);
            const int xcol = x0 + (i & 1) * 16 + lq;
            if (y < Hh && xcol < Ww) {
                float* hp = hid + ((size_t)n * Cc + kb) * Pp + y * Ww + xcol;
                hp[0]              = fmaxf(acc[m][i].x + b0,  0.f);
                hp[Pp]             = fmaxf(acc[m][i].y + b1v, 0.f);
                hp[2 * Pp]         = fmaxf(acc[m][i].z + b2v, 0.f);
                hp[3 * (size_t)Pp] = fmaxf(acc[m][i].w + b3v, 0.f);
            }
        }
    }
}

// ---------------------------------------------------------------------------
// Kernel 2: 1x1 conv to 81 logits + bias, softmax over 81, argmax over 80.
// ---------------------------------------------------------------------------
__global__ __launch_bounds__(256, 2)
void conv1x1_softmax(const float* __restrict__ hid, const float* __restrict__ w2,
                     const float* __restrict__ b2, float* __restrict__ logits,
                     float* __restrict__ pmap, int* __restrict__ cmap)
{
    __shared__ float w2s[64 * 84];   // [c_l][j], j padded 81->84 with zeros
    const int tid = threadIdx.x;
    const int p   = blockIdx.x * 256 + tid;
    const int n   = blockIdx.y;
    const bool valid = (p < Pp);
    const int psafe = valid ? p : 0;

    float acc[84];
#pragma unroll
    for (int j = 0; j < 84; ++j) acc[j] = 0.f;

#pragma unroll 1
    for (int c0 = 0; c0 < Cc; c0 += 64) {
        __syncthreads();
#pragma unroll
        for (int i = 0; i < 21; ++i) {   // 21*256 == 64*84
            int q  = i * 256 + tid;
            int cl = q / 84;
            int j  = q - cl * 84;
            float v = 0.f;
            if (j < NC1) v = w2[j * 256 + c0 + cl];
            w2s[cl * 84 + j] = v;
        }
        __syncthreads();

        const float* hptr = hid + ((size_t)n * Cc + c0) * Pp + psafe;
#pragma unroll 2
        for (int cl = 0; cl < 64; ++cl) {
            float h = hptr[(size_t)cl * Pp];
            const float4* wrow = (const float4*)(&w2s[cl * 84]);
#pragma unroll
            for (int f = 0; f < 21; ++f) {
                float4 wv = wrow[f];
                acc[f * 4 + 0] = fmaf(wv.x, h, acc[f * 4 + 0]);
                acc[f * 4 + 1] = fmaf(wv.y, h, acc[f * 4 + 1]);
                acc[f * 4 + 2] = fmaf(wv.z, h, acc[f * 4 + 2]);
                acc[f * 4 + 3] = fmaf(wv.w, h, acc[f * 4 + 3]);
            }
        }
    }

    if (valid) {
#pragma unroll
        for (int j = 0; j < NC1; ++j) acc[j] += b2[j];

        float* lp = logits + (size_t)n * NC1 * Pp + p;
#pragma unroll
        for (int j = 0; j < NC1; ++j) lp[(size_t)j * Pp] = acc[j];

        float m = -3.4e38f;
#pragma unroll
        for (int j = 0; j < NC1; ++j) m = fmaxf(m, acc[j]);
        float s = 0.f;
#pragma unroll
        for (int j = 0; j < NC1; ++j) s += __expf(acc[j] - m);
        float best = -3.4e38f; int bi = 0;
#pragma unroll
        for (int j = 0; j < NCLS; ++j) {   // first occurrence wins (strict >)
            if (acc[j] > best) { best = acc[j]; bi = j; }
        }
        pmap[n * Pp + p] = __expf(best - m) / s;
        cmap[n * Pp + p] = bi;
    }
}

// ---------------------------------------------------------------------------
// Kernel 3: score = p + 1{local max}.
// ---------------------------------------------------------------------------
__global__ void local_score(const float* __restrict__ pmap, const int* __restrict__ cmap,
                            float* __restrict__ scores)
{
    int p = blockIdx.x * 256 + threadIdx.x;
    int n = blockIdx.y;
    if (p >= Pp) return;
    int base = n * Pp;
    float pv = pmap[base + p];
    int   c  = cmap[base + p];
    int y = p / Ww, xc = p - y * Ww;
    bool ok = (pv >= 1e-6f);
#pragma unroll
    for (int dy = -1; dy <= 1; ++dy)
#pragma unroll
        for (int dx = -1; dx <= 1; ++dx) {
            if (dy == 0 && dx == 0) continue;
            int yy = y + dy, xx = xc + dx;
            if (yy >= 0 && yy < Hh && xx >= 0 && xx < Ww) {
                int q = base + yy * Ww + xx;
                if (cmap[q] == c && pmap[q] > pv) ok = false;
            }
        }
    scores[base + p] = pv + (ok ? 1.f : 0.f);
}

// ---------------------------------------------------------------------------
// Kernel 4: per-batch top-100 (value desc, index asc on ties) + gathers.
// ---------------------------------------------------------------------------
__global__ __launch_bounds__(256)
void topk_gather(const float* __restrict__ scores, const float* __restrict__ x,
                 const float* __restrict__ pos, float* __restrict__ oprop,
                 float* __restrict__ opos)
{
    __shared__ float sv[Pp];                 // 60.8 KB
    __shared__ int sidx[KTOP];
    __shared__ unsigned long long red[4];
    const int tid = threadIdx.x;
    const int n   = blockIdx.x;

    for (int i = tid; i < Pp; i += 256) sv[i] = scores[n * Pp + i];
    __syncthreads();

    for (int it = 0; it < KTOP; ++it) {
        unsigned long long best = 0ull;
        for (int i = tid; i < Pp; i += 256) {
            unsigned fb = __float_as_uint(sv[i]);   // scores > 0 => monotone bits
            unsigned long long key =
                ((unsigned long long)fb << 32) | (unsigned)(0xFFFF - i);
            best = key > best ? key : best;
        }
#pragma unroll
        for (int off = 32; off > 0; off >>= 1) {
            unsigned long long o = __shfl_down(best, off, 64);
            best = o > best ? o : best;
        }
        if ((tid & 63) == 0) red[tid >> 6] = best;
        __syncthreads();
        if (tid == 0) {
            unsigned long long b = red[0];
            b = red[1] > b ? red[1] : b;
            b = red[2] > b ? red[2] : b;
            b = red[3] > b ? red[3] : b;
            int idx = 0xFFFF - (int)(b & 0xFFFFFFFFull);
            sidx[it] = idx;
            sv[idx]  = 0.f;                  // remove winner
        }
        __syncthreads();
    }

    for (int t = tid; t < Cc * KTOP; t += 256) {
        int c = t / KTOP;
        int i = t - c * KTOP;
        int idx = sidx[i];
        oprop[n * Cc * KTOP + c * KTOP + i] = x[((size_t)n * Cc + c) * Pp + idx];
        opos [n * Cc * KTOP + c * KTOP + i] = pos[(size_t)c * Pp + idx];
    }
}

// ---------------------------------------------------------------------------
extern "C" void kernel_launch(void* const* d_in, const int* in_sizes, int n_in,
                              void* d_out, int out_size, void* d_ws, size_t ws_size,
                              hipStream_t stream)
{
    const float* x   = (const float*)d_in[0];
    const float* pos = (const float*)d_in[1];
    const float* w1  = (const float*)d_in[2];
    const float* b1  = (const float*)d_in[3];
    const float* w2  = (const float*)d_in[4];
    const float* b2  = (const float*)d_in[5];

    float* out    = (float*)d_out;
    float* oprop  = out;                                         // (8,256,100)
    float* oposE  = out + (size_t)NBATCH * Cc * KTOP;            // (8,256,100)
    float* logits = out + (size_t)2 * NBATCH * Cc * KTOP;        // (8,81,100,152)

    // wpk (2.36 MB, bf16 fragment-ordered w1) borrows the logits region:
    // written by pack_w, consumed by conv3x3_mfma, overwritten by conv1x1.
    unsigned short* wpk = (unsigned short*)logits;

    // workspace: hid (124.5 MB) | xTpad (128.7 MB) | pmap | cmap | scores
    float* ws  = (float*)d_ws;
    float* hid = ws;                                             // 8*256*15200 f32
    unsigned short* xT = (unsigned short*)(ws + (size_t)NBATCH * Cc * Pp);
    char* after_xt = (char*)xT + (size_t)NBATCH * XT_BATCH_BYTES;
    float* pmap   = (float*)after_xt;                            // 8*15200
    int*   cmap   = (int*)(pmap + (size_t)NBATCH * Pp);          // 8*15200
    float* scores = (float*)(cmap + (size_t)NBATCH * Pp);        // 8*15200

    pack_w<<<256, 256, 0, stream>>>(w1, wpk);
    pack_x<<<dim3(PROWS, Cc, NBATCH), 256, 0, stream>>>(x, xT);
    // 13 row-blocks (8 rows) x 5 col-blocks (32 cols) = 65 pixel tiles
    conv3x3_mfma<<<dim3(65, 2, NBATCH), 512, 0, stream>>>(
        xT, wpk, b1, hid);
    conv1x1_softmax<<<dim3((Pp + 255) / 256, NBATCH), 256, 0, stream>>>(
        hid, w2, b2, logits, pmap, cmap);
    local_score<<<dim3((Pp + 255) / 256, NBATCH), 256, 0, stream>>>(
        pmap, cmap, scores);
    topk_gather<<<NBATCH, 256, 0, stream>>>(scores, x, pos, oprop, oposE);
}

// Round 2
// 1219.555 us; speedup vs baseline: 1.4262x; 1.1925x over previous
//
#include <hip/hip_runtime.h>
#include <hip/hip_bf16.h>

// Problem constants
#define Hh    100
#define Ww    152
#define Pp    15200        // H*W
#define Cc    256
#define NBATCH 8
#define NC1   81
#define NCLS  80
#define KTOP  100

// padded x-tensor geometry (pixel-major bf16 hi/lo)
#define PROWS 102          // rows -1..100
#define PCOLS 154          // cols -1..152
#define PIXB  1024         // bytes per padded pixel: 256 hi + 256 lo bf16
#define XT_BATCH_BYTES ((size_t)PROWS * PCOLS * PIXB)   // 16,084,992

typedef __attribute__((ext_vector_type(8))) short  bf16x8;
typedef __attribute__((ext_vector_type(4))) float  f32x4;

__device__ __forceinline__ unsigned short bf16_bits(float v) {
    __hip_bfloat16 h = __float2bfloat16(v);
    return *(unsigned short*)&h;
}
__device__ __forceinline__ float bf16_back(float v) {
    __hip_bfloat16 h = __float2bfloat16(v);
    return __bfloat162float(h);
}

typedef __attribute__((address_space(1))) const void GV;
typedef __attribute__((address_space(3))) void LV;
__device__ __forceinline__ void gload_lds16(const void* g, void* l) {
    __builtin_amdgcn_global_load_lds((GV*)g, (LV*)l, 16, 0, 0);
}

// ---------------------------------------------------------------------------
// Kernel 0a: pack w1 (OIHW fp32) into A-fragment order, bf16 hi/lo.
// Region r = ((s*9+t)*2+prec): 16 M-tiles x 64 lanes x 8 bf16 = 8192 shorts.
// Within region: mt=k>>4; lane=quad(c)*16 + (k&15); j=c&7.
// ---------------------------------------------------------------------------
__global__ void pack_w(const float* __restrict__ w1, unsigned short* __restrict__ wpk)
{
    int id = blockIdx.x * 256 + threadIdx.x;    // 0..65535
    int k = id >> 8, c = id & 255;
#pragma unroll
    for (int t = 0; t < 9; ++t) {
        float v = w1[(size_t)(k * 256 + c) * 9 + t];
        unsigned short hi = bf16_bits(v);
        unsigned short lo = bf16_bits(v - bf16_back(v));
        int region = ((c >> 5) * 9 + t) * 2;
        int base   = region * 8192;
        int pos    = (k >> 4) * 512 + ((c >> 3) & 3) * 128 + (k & 15) * 8 + (c & 7);
        wpk[base + pos]        = hi;
        wpk[base + 8192 + pos] = lo;
    }
}

// ---------------------------------------------------------------------------
// Kernel 0b: pack x into zero-padded pixel-major bf16 hi/lo via LDS transpose.
// Old version wrote 2 B scattered stores at 1 KB stride (partial-sector RMW).
// New: block = (col-chunk of 64 padded cols) x (one padded row) x n.
//   load phase : 4 waves read x[n][c][yy][x0..x0+63] contiguous 256 B rows,
//                write ls[col][c] (stride 257 -> conflict-free).
//   store phase: per col, 256 threads = 256 channels, write [256 hi|256 lo]
//                contiguous (128 B per wave-store, full 32 B sectors).
// ---------------------------------------------------------------------------
__global__ __launch_bounds__(256)
void pack_x(const float* __restrict__ x, unsigned short* __restrict__ xT)
{
    __shared__ float ls[64][257];      // 65,792 B
    const int tid   = threadIdx.x;
    const int chunk = blockIdx.x;      // 0..2 (padded-col chunks of 64)
    const int row   = blockIdx.y;      // 0..101
    const int n     = blockIdx.z;
    const int c0    = chunk * 64;
    const int yy    = row - 1;
    const bool rowok = ((unsigned)yy < (unsigned)Hh);

    const int lanec = tid & 63;        // padded col offset this thread loads
    const int xx    = c0 + lanec - 1;  // source col
    const bool colok = ((unsigned)xx < (unsigned)Ww);
    const bool ok = rowok && colok;

    const size_t rbase = ((size_t)n * Cc) * Pp + (size_t)(rowok ? yy : 0) * Ww
                       + (size_t)(colok ? xx : 0);
#pragma unroll 4
    for (int i = 0; i < 64; ++i) {
        const int c = (tid >> 6) + i * 4;          // wave-strided channels
        float v = 0.f;
        if (ok) v = x[rbase + (size_t)c * Pp];
        ls[lanec][c] = v;
    }
    __syncthreads();

    const int cch = tid;               // channel 0..255
#pragma unroll 1
    for (int j = 0; j < 64; ++j) {
        const int pc = c0 + j;
        if (pc >= PCOLS) break;        // uniform
        float v = ls[j][cch];
        unsigned short hi = bf16_bits(v);
        unsigned short lo = bf16_bits(v - bf16_back(v));
        size_t dst = (((size_t)n * PROWS + row) * PCOLS + pc) * 512 + cch;
        xT[dst]       = hi;
        xT[dst + 256] = lo;
    }
}

// ---------------------------------------------------------------------------
// Kernel 1: 3x3 conv (SAME) + bias + ReLU via MFMA bf16x3 split.
// De-lockstep rewrite:
//   Block: 512 thr = 8 waves (2 wm x 4 wn). Out 128 ch x (8 rows x 32 cols).
//   B: per s, halo 10x34 px x [32ch hi|32ch lo] = 128 B/px XOR-swizzled,
//      double-buffered (2 x 48 KB LDS), staged via global_load_lds at s-top.
//   A: DIRECT global loads from fragment-ordered wpk (coalesced, L1/L2-hot;
//      4 waves per wm share the same 8 KB slice -> L1 serves repeats).
//   Both A and B fragments register-double-buffered across taps (load t+1
//      before MFMA of t). NO per-tap barriers: one __syncthreads per s, so
//      waves free-run across the 9 taps and reads overlap other waves' MFMA.
// MFMA issue order identical to previous version -> bitwise-same output.
// LDS 96 KB -> 1 block/CU, 8 waves; VGPR ~210 (acc 64 + 128 frag) <= 256.
// ---------------------------------------------------------------------------
#define BBUFB 49152

__global__ __launch_bounds__(512, 2)
void conv3x3_mfma(const unsigned short* __restrict__ xT,
                  const unsigned short* __restrict__ wpk,
                  const float* __restrict__ b1, float* __restrict__ hid)
{
    __shared__ f32x4 ldsbuf[6144];           // 98,304 B = 2 B-buffers
    char* L = (char*)ldsbuf;

    const int tid  = threadIdx.x;
    const int lane = tid & 63;
    const int wv   = tid >> 6;               // 0..7
    const int wm   = wv >> 2;                // 0..1
    const int wn   = wv & 3;                 // 0..3
    const int quad = lane >> 4, lq = lane & 15;

    const int bx = blockIdx.x;               // 0..64 (13 row-blocks x 5 col-blocks)
    const int rb = bx / 5, cb = bx - rb * 5;
    const int y0 = rb * 8;                   // first output row of tile
    const int x0 = cb * 32;                  // first output col of tile
    const int k0 = blockIdx.y * 128;
    const int n  = blockIdx.z;

    const char* xb = (const char*)xT + (size_t)n * XT_BATCH_BYTES;
    // per-lane A base: wpk + m-tile base for this block/wave + lane slot
    const char* abase = (const char*)wpk + (size_t)(k0 >> 4) * 1024
                      + (size_t)(wm * 4) * 1024 + (size_t)lane * 16;

    // staging constants (inverse-swizzled global source, linear LDS dest)
    const unsigned kslot = (lane & 7) ^ (lane >> 3);
    const size_t chnbase = (kslot < 4) ? (size_t)(kslot * 16)
                                       : (size_t)(448 + kslot * 16);

    auto stageB = [&](int s) {
        char* bdst = L + (size_t)(s & 1) * BBUFB;
        const size_t chn = (size_t)s * 64 + chnbase;
#pragma unroll
        for (int k6 = 0; k6 < 6; ++k6) {
            const int j   = wv + 8 * k6;                 // 0..47
            const int pix = 8 * j + (lane >> 3);         // 0..383
            const int r   = pix / 34;
            const int c   = pix - r * 34;
            int prow = y0 + r; prow = prow < 102 ? prow : 101;
            const char* g = xb + (((size_t)(prow * 154 + x0 + c)) << 10) + chn;
            gload_lds16(g, bdst + (size_t)j * 1024);
        }
    };

    auto loadA = [&](int u, bf16x8 (&ah)[4], bf16x8 (&al)[4]) {
        const char* p0 = abase + (size_t)u * 32768;
#pragma unroll
        for (int m = 0; m < 4; ++m) {
            ah[m] = *(const bf16x8*)(p0 + m * 1024);
            al[m] = *(const bf16x8*)(p0 + m * 1024 + 16384);
        }
    };

    const int pix0 = wn * 2 * 34 + lq;
    auto readB = [&](int s, int t, bf16x8 (&bh)[4], bf16x8 (&bl)[4]) {
        const char* Bb = L + (size_t)(s & 1) * BBUFB;
        const int ty = t / 3, tx = t - ty * 3;
        const int pb0 = pix0 + ty * 34 + tx;
#pragma unroll
        for (int i = 0; i < 4; ++i) {
            const int pix = pb0 + (i >> 1) * 34 + (i & 1) * 16;
            const int a = pix * 128 + ((quad ^ (pix & 7)) << 4);
            bh[i] = *(const bf16x8*)(Bb + a);
            bl[i] = *(const bf16x8*)(Bb + (a ^ 64));
        }
    };

    f32x4 acc[4][4];
#pragma unroll
    for (int a = 0; a < 4; ++a)
#pragma unroll
        for (int b = 0; b < 4; ++b) acc[a][b] = 0;

    auto mfma48 = [&](bf16x8 (&ah)[4], bf16x8 (&al)[4],
                      bf16x8 (&bh)[4], bf16x8 (&bl)[4]) {
        __builtin_amdgcn_s_setprio(1);
#pragma unroll
        for (int m = 0; m < 4; ++m)
#pragma unroll
            for (int i = 0; i < 4; ++i)
                acc[m][i] = __builtin_amdgcn_mfma_f32_16x16x32_bf16(ah[m], bh[i], acc[m][i], 0, 0, 0);
#pragma unroll
        for (int m = 0; m < 4; ++m)
#pragma unroll
            for (int i = 0; i < 4; ++i)
                acc[m][i] = __builtin_amdgcn_mfma_f32_16x16x32_bf16(ah[m], bl[i], acc[m][i], 0, 0, 0);
#pragma unroll
        for (int m = 0; m < 4; ++m)
#pragma unroll
            for (int i = 0; i < 4; ++i)
                acc[m][i] = __builtin_amdgcn_mfma_f32_16x16x32_bf16(al[m], bh[i], acc[m][i], 0, 0, 0);
        __builtin_amdgcn_s_setprio(0);
    };

    bf16x8 ah[2][4], al[2][4], bh[2][4], bl[2][4];

    // prologue: stage B(0); then prime frags for (s=0, t=0)
    stageB(0);
    __syncthreads();
    loadA(0, ah[0], al[0]);
    readB(0, 0, bh[0], bl[0]);

#pragma unroll 1
    for (int s = 0; s < 8; ++s) {
        if (s < 7) stageB(s + 1);              // writes other B half; no sync needed
#pragma unroll
        for (int t = 0; t < 9; ++t) {
            const int cur = t & 1, nx = cur ^ 1;
            if (t < 8) {
                loadA(s * 9 + t + 1, ah[nx], al[nx]);
                readB(s, t + 1, bh[nx], bl[nx]);
            }
            mfma48(ah[cur], al[cur], bh[cur], bl[cur]);
        }
        __syncthreads();                       // drains stage loads; flips B half
        if (s < 7) {
            loadA((s + 1) * 9, ah[0], al[0]);
            readB(s + 1, 0, bh[0], bl[0]);
        }
    }

    // epilogue: bias + relu; D row = quad*4 + reg
#pragma unroll
    for (int m = 0; m < 4; ++m) {
        const int kb = k0 + wm * 64 + m * 16 + quad * 4;
        const float b0 = b1[kb], b1v = b1[kb + 1], b2v = b1[kb + 2], b3v = b1[kb + 3];
#pragma unroll
        for (int i = 0; i < 4; ++i) {
            const int y = y0 + wn * 2 + (i >> 1);
            const int xcol = x0 + (i & 1) * 16 + lq;
            if (y < Hh && xcol < Ww) {
                float* hp = hid + ((size_t)n * Cc + kb) * Pp + y * Ww + xcol;
                hp[0]              = fmaxf(acc[m][i].x + b0,  0.f);
                hp[Pp]             = fmaxf(acc[m][i].y + b1v, 0.f);
                hp[2 * Pp]         = fmaxf(acc[m][i].z + b2v, 0.f);
                hp[3 * (size_t)Pp] = fmaxf(acc[m][i].w + b3v, 0.f);
            }
        }
    }
}

// ---------------------------------------------------------------------------
// Kernel 2: 1x1 conv to 81 logits + bias, softmax over 81, argmax over 80.
// ---------------------------------------------------------------------------
__global__ __launch_bounds__(256, 2)
void conv1x1_softmax(const float* __restrict__ hid, const float* __restrict__ w2,
                     const float* __restrict__ b2, float* __restrict__ logits,
                     float* __restrict__ pmap, int* __restrict__ cmap)
{
    __shared__ float w2s[64 * 84];   // [c_l][j], j padded 81->84 with zeros
    const int tid = threadIdx.x;
    const int p   = blockIdx.x * 256 + tid;
    const int n   = blockIdx.y;
    const bool valid = (p < Pp);
    const int psafe = valid ? p : 0;

    float acc[84];
#pragma unroll
    for (int j = 0; j < 84; ++j) acc[j] = 0.f;

#pragma unroll 1
    for (int c0 = 0; c0 < Cc; c0 += 64) {
        __syncthreads();
#pragma unroll
        for (int i = 0; i < 21; ++i) {   // 21*256 == 64*84
            int q  = i * 256 + tid;
            int cl = q / 84;
            int j  = q - cl * 84;
            float v = 0.f;
            if (j < NC1) v = w2[j * 256 + c0 + cl];
            w2s[cl * 84 + j] = v;
        }
        __syncthreads();

        const float* hptr = hid + ((size_t)n * Cc + c0) * Pp + psafe;
#pragma unroll 2
        for (int cl = 0; cl < 64; ++cl) {
            float h = hptr[(size_t)cl * Pp];
            const float4* wrow = (const float4*)(&w2s[cl * 84]);
#pragma unroll
            for (int f = 0; f < 21; ++f) {
                float4 wv = wrow[f];
                acc[f * 4 + 0] = fmaf(wv.x, h, acc[f * 4 + 0]);
                acc[f * 4 + 1] = fmaf(wv.y, h, acc[f * 4 + 1]);
                acc[f * 4 + 2] = fmaf(wv.z, h, acc[f * 4 + 2]);
                acc[f * 4 + 3] = fmaf(wv.w, h, acc[f * 4 + 3]);
            }
        }
    }

    if (valid) {
#pragma unroll
        for (int j = 0; j < NC1; ++j) acc[j] += b2[j];

        float* lp = logits + (size_t)n * NC1 * Pp + p;
#pragma unroll
        for (int j = 0; j < NC1; ++j) lp[(size_t)j * Pp] = acc[j];

        float m = -3.4e38f;
#pragma unroll
        for (int j = 0; j < NC1; ++j) m = fmaxf(m, acc[j]);
        float s = 0.f;
#pragma unroll
        for (int j = 0; j < NC1; ++j) s += __expf(acc[j] - m);
        float best = -3.4e38f; int bi = 0;
#pragma unroll
        for (int j = 0; j < NCLS; ++j) {   // first occurrence wins (strict >)
            if (acc[j] > best) { best = acc[j]; bi = j; }
        }
        pmap[n * Pp + p] = __expf(best - m) / s;
        cmap[n * Pp + p] = bi;
    }
}

// ---------------------------------------------------------------------------
// Kernel 3: score = p + 1{local max}.
// ---------------------------------------------------------------------------
__global__ void local_score(const float* __restrict__ pmap, const int* __restrict__ cmap,
                            float* __restrict__ scores)
{
    int p = blockIdx.x * 256 + threadIdx.x;
    int n = blockIdx.y;
    if (p >= Pp) return;
    int base = n * Pp;
    float pv = pmap[base + p];
    int   c  = cmap[base + p];
    int y = p / Ww, xc = p - y * Ww;
    bool ok = (pv >= 1e-6f);
#pragma unroll
    for (int dy = -1; dy <= 1; ++dy)
#pragma unroll
        for (int dx = -1; dx <= 1; ++dx) {
            if (dy == 0 && dx == 0) continue;
            int yy = y + dy, xx = xc + dx;
            if (yy >= 0 && yy < Hh && xx >= 0 && xx < Ww) {
                int q = base + yy * Ww + xx;
                if (cmap[q] == c && pmap[q] > pv) ok = false;
            }
        }
    scores[base + p] = pv + (ok ? 1.f : 0.f);
}

// ---------------------------------------------------------------------------
// Kernel 4: per-batch top-100 (value desc, index asc on ties) + gathers.
// ---------------------------------------------------------------------------
__global__ __launch_bounds__(256)
void topk_gather(const float* __restrict__ scores, const float* __restrict__ x,
                 const float* __restrict__ pos, float* __restrict__ oprop,
                 float* __restrict__ opos)
{
    __shared__ float sv[Pp];                 // 60.8 KB
    __shared__ int sidx[KTOP];
    __shared__ unsigned long long red[4];
    const int tid = threadIdx.x;
    const int n   = blockIdx.x;

    for (int i = tid; i < Pp; i += 256) sv[i] = scores[n * Pp + i];
    __syncthreads();

    for (int it = 0; it < KTOP; ++it) {
        unsigned long long best = 0ull;
        for (int i = tid; i < Pp; i += 256) {
            unsigned fb = __float_as_uint(sv[i]);   // scores > 0 => monotone bits
            unsigned long long key =
                ((unsigned long long)fb << 32) | (unsigned)(0xFFFF - i);
            best = key > best ? key : best;
        }
#pragma unroll
        for (int off = 32; off > 0; off >>= 1) {
            unsigned long long o = __shfl_down(best, off, 64);
            best = o > best ? o : best;
        }
        if ((tid & 63) == 0) red[tid >> 6] = best;
        __syncthreads();
        if (tid == 0) {
            unsigned long long b = red[0];
            b = red[1] > b ? red[1] : b;
            b = red[2] > b ? red[2] : b;
            b = red[3] > b ? red[3] : b;
            int idx = 0xFFFF - (int)(b & 0xFFFFFFFFull);
            sidx[it] = idx;
            sv[idx]  = 0.f;                  // remove winner
        }
        __syncthreads();
    }

    for (int t = tid; t < Cc * KTOP; t += 256) {
        int c = t / KTOP;
        int i = t - c * KTOP;
        int idx = sidx[i];
        oprop[n * Cc * KTOP + c * KTOP + i] = x[((size_t)n * Cc + c) * Pp + idx];
        opos [n * Cc * KTOP + c * KTOP + i] = pos[(size_t)c * Pp + idx];
    }
}

// ---------------------------------------------------------------------------
extern "C" void kernel_launch(void* const* d_in, const int* in_sizes, int n_in,
                              void* d_out, int out_size, void* d_ws, size_t ws_size,
                              hipStream_t stream)
{
    const float* x   = (const float*)d_in[0];
    const float* pos = (const float*)d_in[1];
    const float* w1  = (const float*)d_in[2];
    const float* b1  = (const float*)d_in[3];
    const float* w2  = (const float*)d_in[4];
    const float* b2  = (const float*)d_in[5];

    float* out    = (float*)d_out;
    float* oprop  = out;                                         // (8,256,100)
    float* oposE  = out + (size_t)NBATCH * Cc * KTOP;            // (8,256,100)
    float* logits = out + (size_t)2 * NBATCH * Cc * KTOP;        // (8,81,100,152)

    // wpk (2.36 MB, bf16 fragment-ordered w1) borrows the logits region:
    // written by pack_w, consumed by conv3x3_mfma, overwritten by conv1x1.
    unsigned short* wpk = (unsigned short*)logits;

    // workspace: hid (124.5 MB) | xTpad (128.7 MB) | pmap | cmap | scores
    float* ws  = (float*)d_ws;
    float* hid = ws;                                             // 8*256*15200 f32
    unsigned short* xT = (unsigned short*)(ws + (size_t)NBATCH * Cc * Pp);
    char* after_xt = (char*)xT + (size_t)NBATCH * XT_BATCH_BYTES;
    float* pmap   = (float*)after_xt;                            // 8*15200
    int*   cmap   = (int*)(pmap + (size_t)NBATCH * Pp);          // 8*15200
    float* scores = (float*)(cmap + (size_t)NBATCH * Pp);        // 8*15200

    pack_w<<<256, 256, 0, stream>>>(w1, wpk);
    pack_x<<<dim3(3, PROWS, NBATCH), 256, 0, stream>>>(x, xT);
    // 13 row-blocks (8 rows) x 5 col-blocks (32 cols) = 65 pixel tiles
    conv3x3_mfma<<<dim3(65, 2, NBATCH), 512, 0, stream>>>(
        xT, wpk, b1, hid);
    conv1x1_softmax<<<dim3((Pp + 255) / 256, NBATCH), 256, 0, stream>>>(
        hid, w2, b2, logits, pmap, cmap);
    local_score<<<dim3((Pp + 255) / 256, NBATCH), 256, 0, stream>>>(
        pmap, cmap, scores);
    topk_gather<<<NBATCH, 256, 0, stream>>>(scores, x, pos, oprop, oposE);
}

// Round 3
// 1136.049 us; speedup vs baseline: 1.5310x; 1.0735x over previous
//
#include <hip/hip_runtime.h>
#include <hip/hip_bf16.h>

// Problem constants
#define Hh    100
#define Ww    152
#define Pp    15200        // H*W
#define Cc    256
#define NBATCH 8
#define NC1   81
#define NCLS  80
#define KTOP  100

// padded x-tensor geometry (pixel-major bf16 hi/lo)
#define PROWS 102          // rows -1..100
#define PCOLS 154          // cols -1..152
#define PIXB  1024         // bytes per padded pixel: 256 hi + 256 lo bf16
#define XT_BATCH_BYTES ((size_t)PROWS * PCOLS * PIXB)   // 16,084,992

typedef __attribute__((ext_vector_type(8))) short  bf16x8;
typedef __attribute__((ext_vector_type(4))) float  f32x4;

__device__ __forceinline__ unsigned short bf16_bits(float v) {
    __hip_bfloat16 h = __float2bfloat16(v);
    return *(unsigned short*)&h;
}
__device__ __forceinline__ float bf16_back(float v) {
    __hip_bfloat16 h = __float2bfloat16(v);
    return __bfloat162float(h);
}

typedef __attribute__((address_space(1))) const void GV;
typedef __attribute__((address_space(3))) void LV;
__device__ __forceinline__ void gload_lds16(const void* g, void* l) {
    __builtin_amdgcn_global_load_lds((GV*)g, (LV*)l, 16, 0, 0);
}

// ---------------------------------------------------------------------------
// Kernel 0a: pack w1 (OIHW fp32) into A-fragment order, bf16 hi/lo.
// ---------------------------------------------------------------------------
__global__ void pack_w(const float* __restrict__ w1, unsigned short* __restrict__ wpk)
{
    int id = blockIdx.x * 256 + threadIdx.x;    // 0..65535
    int k = id >> 8, c = id & 255;
#pragma unroll
    for (int t = 0; t < 9; ++t) {
        float v = w1[(size_t)(k * 256 + c) * 9 + t];
        unsigned short hi = bf16_bits(v);
        unsigned short lo = bf16_bits(v - bf16_back(v));
        int region = ((c >> 5) * 9 + t) * 2;
        int base   = region * 8192;
        int pos    = (k >> 4) * 512 + ((c >> 3) & 3) * 128 + (k & 15) * 8 + (c & 7);
        wpk[base + pos]        = hi;
        wpk[base + 8192 + pos] = lo;
    }
}

// ---------------------------------------------------------------------------
// Kernel 0b: pack x into zero-padded pixel-major bf16 hi/lo via LDS transpose.
// ---------------------------------------------------------------------------
__global__ __launch_bounds__(256)
void pack_x(const float* __restrict__ x, unsigned short* __restrict__ xT)
{
    __shared__ float ls[64][257];      // 65,792 B
    const int tid   = threadIdx.x;
    const int chunk = blockIdx.x;      // 0..2 (padded-col chunks of 64)
    const int row   = blockIdx.y;      // 0..101
    const int n     = blockIdx.z;
    const int c0    = chunk * 64;
    const int yy    = row - 1;
    const bool rowok = ((unsigned)yy < (unsigned)Hh);

    const int lanec = tid & 63;        // padded col offset this thread loads
    const int xx    = c0 + lanec - 1;  // source col
    const bool colok = ((unsigned)xx < (unsigned)Ww);
    const bool ok = rowok && colok;

    const size_t rbase = ((size_t)n * Cc) * Pp + (size_t)(rowok ? yy : 0) * Ww
                       + (size_t)(colok ? xx : 0);
#pragma unroll 4
    for (int i = 0; i < 64; ++i) {
        const int c = (tid >> 6) + i * 4;          // wave-strided channels
        float v = 0.f;
        if (ok) v = x[rbase + (size_t)c * Pp];
        ls[lanec][c] = v;
    }
    __syncthreads();

    const int cch = tid;               // channel 0..255
#pragma unroll 1
    for (int j = 0; j < 64; ++j) {
        const int pc = c0 + j;
        if (pc >= PCOLS) break;        // uniform
        float v = ls[j][cch];
        unsigned short hi = bf16_bits(v);
        unsigned short lo = bf16_bits(v - bf16_back(v));
        size_t dst = (((size_t)n * PROWS + row) * PCOLS + pc) * 512 + cch;
        xT[dst]       = hi;
        xT[dst + 256] = lo;
    }
}

// ---------------------------------------------------------------------------
// Kernel 1: 3x3 conv (SAME) + bias + ReLU via MFMA bf16x3 split.
// Round-3: sched_barrier-pinned register double-buffer (frags t and t+1
// co-live -> VGPR ~200, loads of t+1 in flight across mfma48(t)), plus
// bijective XCD swizzle (1040 = 8 x 130): XCD j owns batch n=j, (bx,k0)
// pairs adjacent so each B halo staged twice back-to-back L2-hot.
// MFMA issue order identical -> bitwise-same output.
// ---------------------------------------------------------------------------
#define BBUFB 49152

__global__ __launch_bounds__(512, 2)
void conv3x3_mfma(const unsigned short* __restrict__ xT,
                  const unsigned short* __restrict__ wpk,
                  const float* __restrict__ b1, float* __restrict__ hid)
{
    __shared__ f32x4 ldsbuf[6144];           // 98,304 B = 2 B-buffers
    char* L = (char*)ldsbuf;

    const int tid  = threadIdx.x;
    const int lane = tid & 63;
    const int wv   = tid >> 6;               // 0..7
    const int wm   = wv >> 2;                // 0..1
    const int wn   = wv & 3;                 // 0..3
    const int quad = lane >> 4, lq = lane & 15;

    // bijective XCD swizzle: hwflat in [0,1040), 1040 = 8*130
    const int hwflat  = blockIdx.x + 65 * (blockIdx.y + 2 * blockIdx.z);
    const int logical = (hwflat & 7) * 130 + (hwflat >> 3);
    const int n   = logical / 130;           // XCD j -> batch j
    const int rem = logical - n * 130;
    const int bx  = rem >> 1;                // 0..64
    const int k0b = rem & 1;

    const int rb = bx / 5, cb = bx - rb * 5;
    const int y0 = rb * 8;                   // first output row of tile
    const int x0 = cb * 32;                  // first output col of tile
    const int k0 = k0b * 128;

    const char* xb = (const char*)xT + (size_t)n * XT_BATCH_BYTES;
    // per-lane A base: wpk + m-tile base for this block/wave + lane slot
    const char* abase = (const char*)wpk + (size_t)(k0 >> 4) * 1024
                      + (size_t)(wm * 4) * 1024 + (size_t)lane * 16;

    // staging constants (inverse-swizzled global source, linear LDS dest)
    const unsigned kslot = (lane & 7) ^ (lane >> 3);
    const size_t chnbase = (kslot < 4) ? (size_t)(kslot * 16)
                                       : (size_t)(448 + kslot * 16);

    auto stageB = [&](int s) {
        char* bdst = L + (size_t)(s & 1) * BBUFB;
        const size_t chn = (size_t)s * 64 + chnbase;
#pragma unroll
        for (int k6 = 0; k6 < 6; ++k6) {
            const int j   = wv + 8 * k6;                 // 0..47
            const int pix = 8 * j + (lane >> 3);         // 0..383
            const int r   = pix / 34;
            const int c   = pix - r * 34;
            int prow = y0 + r; prow = prow < 102 ? prow : 101;
            const char* g = xb + (((size_t)(prow * 154 + x0 + c)) << 10) + chn;
            gload_lds16(g, bdst + (size_t)j * 1024);
        }
    };

    auto loadA = [&](int u, bf16x8 (&ah)[4], bf16x8 (&al)[4]) {
        const char* p0 = abase + (size_t)u * 32768;
#pragma unroll
        for (int m = 0; m < 4; ++m) {
            ah[m] = *(const bf16x8*)(p0 + m * 1024);
            al[m] = *(const bf16x8*)(p0 + m * 1024 + 16384);
        }
    };

    const int pix0 = wn * 2 * 34 + lq;
    auto readB = [&](int s, int t, bf16x8 (&bh)[4], bf16x8 (&bl)[4]) {
        const char* Bb = L + (size_t)(s & 1) * BBUFB;
        const int ty = t / 3, tx = t - ty * 3;
        const int pb0 = pix0 + ty * 34 + tx;
#pragma unroll
        for (int i = 0; i < 4; ++i) {
            const int pix = pb0 + (i >> 1) * 34 + (i & 1) * 16;
            const int a = pix * 128 + ((quad ^ (pix & 7)) << 4);
            bh[i] = *(const bf16x8*)(Bb + a);
            bl[i] = *(const bf16x8*)(Bb + (a ^ 64));
        }
    };

    f32x4 acc[4][4];
#pragma unroll
    for (int a = 0; a < 4; ++a)
#pragma unroll
        for (int b = 0; b < 4; ++b) acc[a][b] = 0;

    auto mfma48 = [&](bf16x8 (&ah)[4], bf16x8 (&al)[4],
                      bf16x8 (&bh)[4], bf16x8 (&bl)[4]) {
        __builtin_amdgcn_s_setprio(1);
#pragma unroll
        for (int m = 0; m < 4; ++m)
#pragma unroll
            for (int i = 0; i < 4; ++i)
                acc[m][i] = __builtin_amdgcn_mfma_f32_16x16x32_bf16(ah[m], bh[i], acc[m][i], 0, 0, 0);
#pragma unroll
        for (int m = 0; m < 4; ++m)
#pragma unroll
            for (int i = 0; i < 4; ++i)
                acc[m][i] = __builtin_amdgcn_mfma_f32_16x16x32_bf16(ah[m], bl[i], acc[m][i], 0, 0, 0);
#pragma unroll
        for (int m = 0; m < 4; ++m)
#pragma unroll
            for (int i = 0; i < 4; ++i)
                acc[m][i] = __builtin_amdgcn_mfma_f32_16x16x32_bf16(al[m], bh[i], acc[m][i], 0, 0, 0);
        __builtin_amdgcn_s_setprio(0);
    };

    bf16x8 ah[2][4], al[2][4], bh[2][4], bl[2][4];

    // prologue: stage B(0); then prime frags for (s=0, t=0)
    stageB(0);
    __syncthreads();
    loadA(0, ah[0], al[0]);
    readB(0, 0, bh[0], bl[0]);

#pragma unroll 1
    for (int s = 0; s < 8; ++s) {
        if (s < 7) stageB(s + 1);              // writes other B half; no sync needed
#pragma unroll
        for (int t = 0; t < 9; ++t) {
            const int cur = t & 1, nx = cur ^ 1;
            if (t < 8) {
                loadA(s * 9 + t + 1, ah[nx], al[nx]);
                readB(s, t + 1, bh[nx], bl[nx]);
            }
            // pin: prefetch(t+1) stays ABOVE, mfma(t) cannot swallow it
            __builtin_amdgcn_sched_barrier(0);
            mfma48(ah[cur], al[cur], bh[cur], bl[cur]);
            __builtin_amdgcn_sched_barrier(0);
        }
        __syncthreads();                       // drains stage loads; flips B half
        if (s < 7) {
            loadA((s + 1) * 9, ah[0], al[0]);
            readB(s + 1, 0, bh[0], bl[0]);
        }
    }

    // epilogue: bias + relu; D row = quad*4 + reg
#pragma unroll
    for (int m = 0; m < 4; ++m) {
        const int kb = k0 + wm * 64 + m * 16 + quad * 4;
        const float b0 = b1[kb], b1v = b1[kb + 1], b2v = b1[kb + 2], b3v = b1[kb + 3];
#pragma unroll
        for (int i = 0; i < 4; ++i) {
            const int y = y0 + wn * 2 + (i >> 1);
            const int xcol = x0 + (i & 1) * 16 + lq;
            if (y < Hh && xcol < Ww) {
                float* hp = hid + ((size_t)n * Cc + kb) * Pp + y * Ww + xcol;
                hp[0]              = fmaxf(acc[m][i].x + b0,  0.f);
                hp[Pp]             = fmaxf(acc[m][i].y + b1v, 0.f);
                hp[2 * Pp]         = fmaxf(acc[m][i].z + b2v, 0.f);
                hp[3 * (size_t)Pp] = fmaxf(acc[m][i].w + b3v, 0.f);
            }
        }
    }
}

// ---------------------------------------------------------------------------
// Kernel 2: 1x1 conv to 81 logits + bias, softmax over 81, argmax over 80.
// ---------------------------------------------------------------------------
__global__ __launch_bounds__(256, 2)
void conv1x1_softmax(const float* __restrict__ hid, const float* __restrict__ w2,
                     const float* __restrict__ b2, float* __restrict__ logits,
                     float* __restrict__ pmap, int* __restrict__ cmap)
{
    __shared__ float w2s[64 * 84];   // [c_l][j], j padded 81->84 with zeros
    const int tid = threadIdx.x;
    const int p   = blockIdx.x * 256 + tid;
    const int n   = blockIdx.y;
    const bool valid = (p < Pp);
    const int psafe = valid ? p : 0;

    float acc[84];
#pragma unroll
    for (int j = 0; j < 84; ++j) acc[j] = 0.f;

#pragma unroll 1
    for (int c0 = 0; c0 < Cc; c0 += 64) {
        __syncthreads();
#pragma unroll
        for (int i = 0; i < 21; ++i) {   // 21*256 == 64*84
            int q  = i * 256 + tid;
            int cl = q / 84;
            int j  = q - cl * 84;
            float v = 0.f;
            if (j < NC1) v = w2[j * 256 + c0 + cl];
            w2s[cl * 84 + j] = v;
        }
        __syncthreads();

        const float* hptr = hid + ((size_t)n * Cc + c0) * Pp + psafe;
#pragma unroll 2
        for (int cl = 0; cl < 64; ++cl) {
            float h = hptr[(size_t)cl * Pp];
            const float4* wrow = (const float4*)(&w2s[cl * 84]);
#pragma unroll
            for (int f = 0; f < 21; ++f) {
                float4 wv = wrow[f];
                acc[f * 4 + 0] = fmaf(wv.x, h, acc[f * 4 + 0]);
                acc[f * 4 + 1] = fmaf(wv.y, h, acc[f * 4 + 1]);
                acc[f * 4 + 2] = fmaf(wv.z, h, acc[f * 4 + 2]);
                acc[f * 4 + 3] = fmaf(wv.w, h, acc[f * 4 + 3]);
            }
        }
    }

    if (valid) {
#pragma unroll
        for (int j = 0; j < NC1; ++j) acc[j] += b2[j];

        float* lp = logits + (size_t)n * NC1 * Pp + p;
#pragma unroll
        for (int j = 0; j < NC1; ++j) lp[(size_t)j * Pp] = acc[j];

        float m = -3.4e38f;
#pragma unroll
        for (int j = 0; j < NC1; ++j) m = fmaxf(m, acc[j]);
        float s = 0.f;
#pragma unroll
        for (int j = 0; j < NC1; ++j) s += __expf(acc[j] - m);
        float best = -3.4e38f; int bi = 0;
#pragma unroll
        for (int j = 0; j < NCLS; ++j) {   // first occurrence wins (strict >)
            if (acc[j] > best) { best = acc[j]; bi = j; }
        }
        pmap[n * Pp + p] = __expf(best - m) / s;
        cmap[n * Pp + p] = bi;
    }
}

// ---------------------------------------------------------------------------
// Kernel 3: score = p + 1{local max}.
// ---------------------------------------------------------------------------
__global__ void local_score(const float* __restrict__ pmap, const int* __restrict__ cmap,
                            float* __restrict__ scores)
{
    int p = blockIdx.x * 256 + threadIdx.x;
    int n = blockIdx.y;
    if (p >= Pp) return;
    int base = n * Pp;
    float pv = pmap[base + p];
    int   c  = cmap[base + p];
    int y = p / Ww, xc = p - y * Ww;
    bool ok = (pv >= 1e-6f);
#pragma unroll
    for (int dy = -1; dy <= 1; ++dy)
#pragma unroll
        for (int dx = -1; dx <= 1; ++dx) {
            if (dy == 0 && dx == 0) continue;
            int yy = y + dy, xx = xc + dx;
            if (yy >= 0 && yy < Hh && xx >= 0 && xx < Ww) {
                int q = base + yy * Ww + xx;
                if (cmap[q] == c && pmap[q] > pv) ok = false;
            }
        }
    scores[base + p] = pv + (ok ? 1.f : 0.f);
}

// ---------------------------------------------------------------------------
// Kernel 4: per-batch top-100 (value desc, index asc on ties) + gathers.
// Round-3 rewrite: 1024 threads (16 waves, 4/SIMD). Per-thread running max
// over its 15 strided elements, kept in a register; per iteration only a
// wave-reduce + tid0 cross-wave max + OWNER-thread rescan (unrolled, latency
// hidden). Composite key identical -> identical selection order.
// ---------------------------------------------------------------------------
__global__ __launch_bounds__(1024)
void topk_gather(const float* __restrict__ scores, const float* __restrict__ x,
                 const float* __restrict__ pos, float* __restrict__ oprop,
                 float* __restrict__ opos)
{
    __shared__ float sv[Pp];                 // 60.8 KB
    __shared__ int sidx[KTOP];
    __shared__ unsigned long long red[16];
    __shared__ unsigned long long bcast;
    const int tid = threadIdx.x;
    const int n   = blockIdx.x;

    for (int i = tid; i < Pp; i += 1024) sv[i] = scores[n * Pp + i];
    __syncthreads();

    auto scan = [&]() -> unsigned long long {
        unsigned long long best = 0ull;
#pragma unroll
        for (int k = 0; k < 15; ++k) {       // 15*1024 = 15360 >= 15200
            const int i = tid + k * 1024;
            if (i < Pp) {
                unsigned fb = __float_as_uint(sv[i]);   // scores>0 => monotone
                unsigned long long key =
                    ((unsigned long long)fb << 32) | (unsigned)(0xFFFF - i);
                best = key > best ? key : best;
            }
        }
        return best;
    };

    unsigned long long mybest = scan();

    for (int it = 0; it < KTOP; ++it) {
        unsigned long long b = mybest;
#pragma unroll
        for (int off = 32; off > 0; off >>= 1) {
            unsigned long long o = __shfl_down(b, off, 64);
            b = o > b ? o : b;
        }
        if ((tid & 63) == 0) red[tid >> 6] = b;
        __syncthreads();
        if (tid == 0) {
            unsigned long long bf = red[0];
#pragma unroll
            for (int w = 1; w < 16; ++w) bf = red[w] > bf ? red[w] : bf;
            int idx = 0xFFFF - (int)(bf & 0xFFFFFFFFull);
            sidx[it] = idx;
            sv[idx]  = 0.f;                  // remove winner
            bcast    = bf;
        }
        __syncthreads();
        const unsigned long long w = bcast;
        const int idx = 0xFFFF - (int)(w & 0xFFFFFFFFull);
        if ((idx & 1023) == tid) mybest = scan();   // only owner rescans
    }

    for (int t = tid; t < Cc * KTOP; t += 1024) {
        int c = t / KTOP;
        int i = t - c * KTOP;
        int idx = sidx[i];
        oprop[n * Cc * KTOP + c * KTOP + i] = x[((size_t)n * Cc + c) * Pp + idx];
        opos [n * Cc * KTOP + c * KTOP + i] = pos[(size_t)c * Pp + idx];
    }
}

// ---------------------------------------------------------------------------
extern "C" void kernel_launch(void* const* d_in, const int* in_sizes, int n_in,
                              void* d_out, int out_size, void* d_ws, size_t ws_size,
                              hipStream_t stream)
{
    const float* x   = (const float*)d_in[0];
    const float* pos = (const float*)d_in[1];
    const float* w1  = (const float*)d_in[2];
    const float* b1  = (const float*)d_in[3];
    const float* w2  = (const float*)d_in[4];
    const float* b2  = (const float*)d_in[5];

    float* out    = (float*)d_out;
    float* oprop  = out;                                         // (8,256,100)
    float* oposE  = out + (size_t)NBATCH * Cc * KTOP;            // (8,256,100)
    float* logits = out + (size_t)2 * NBATCH * Cc * KTOP;        // (8,81,100,152)

    // wpk (2.36 MB, bf16 fragment-ordered w1) borrows the logits region:
    // written by pack_w, consumed by conv3x3_mfma, overwritten by conv1x1.
    unsigned short* wpk = (unsigned short*)logits;

    // workspace: hid (124.5 MB) | xTpad (128.7 MB) | pmap | cmap | scores
    float* ws  = (float*)d_ws;
    float* hid = ws;                                             // 8*256*15200 f32
    unsigned short* xT = (unsigned short*)(ws + (size_t)NBATCH * Cc * Pp);
    char* after_xt = (char*)xT + (size_t)NBATCH * XT_BATCH_BYTES;
    float* pmap   = (float*)after_xt;                            // 8*15200
    int*   cmap   = (int*)(pmap + (size_t)NBATCH * Pp);          // 8*15200
    float* scores = (float*)(cmap + (size_t)NBATCH * Pp);        // 8*15200

    pack_w<<<256, 256, 0, stream>>>(w1, wpk);
    pack_x<<<dim3(3, PROWS, NBATCH), 256, 0, stream>>>(x, xT);
    // 13 row-blocks (8 rows) x 5 col-blocks (32 cols) = 65 pixel tiles
    conv3x3_mfma<<<dim3(65, 2, NBATCH), 512, 0, stream>>>(
        xT, wpk, b1, hid);
    conv1x1_softmax<<<dim3((Pp + 255) / 256, NBATCH), 256, 0, stream>>>(
        hid, w2, b2, logits, pmap, cmap);
    local_score<<<dim3((Pp + 255) / 256, NBATCH), 256, 0, stream>>>(
        pmap, cmap, scores);
    topk_gather<<<NBATCH, 1024, 0, stream>>>(scores, x, pos, oprop, oposE);
}

// Round 4
// 1116.931 us; speedup vs baseline: 1.5572x; 1.0171x over previous
//
#include <hip/hip_runtime.h>
#include <hip/hip_bf16.h>

// Problem constants
#define Hh    100
#define Ww    152
#define Pp    15200        // H*W
#define Cc    256
#define NBATCH 8
#define NC1   81
#define NCLS  80
#define KTOP  100

// padded x-tensor geometry (pixel-major bf16 hi/lo)
#define PROWS 102          // rows -1..100
#define PCOLS 154          // cols -1..152
#define PIXB  1024         // bytes per padded pixel: 256 hi + 256 lo bf16
#define XT_BATCH_BYTES ((size_t)PROWS * PCOLS * PIXB)   // 16,084,992

typedef __attribute__((ext_vector_type(8))) short  bf16x8;
typedef __attribute__((ext_vector_type(4))) float  f32x4;

__device__ __forceinline__ unsigned short bf16_bits(float v) {
    __hip_bfloat16 h = __float2bfloat16(v);
    return *(unsigned short*)&h;
}
__device__ __forceinline__ float bf16_back(float v) {
    __hip_bfloat16 h = __float2bfloat16(v);
    return __bfloat162float(h);
}

typedef __attribute__((address_space(1))) const void GV;
typedef __attribute__((address_space(3))) void LV;
__device__ __forceinline__ void gload_lds16(const void* g, void* l) {
    __builtin_amdgcn_global_load_lds((GV*)g, (LV*)l, 16, 0, 0);
}

// ---------------------------------------------------------------------------
// Kernel 0a: pack w1 (OIHW fp32) into A-fragment order, bf16 hi/lo.
// ---------------------------------------------------------------------------
__global__ void pack_w(const float* __restrict__ w1, unsigned short* __restrict__ wpk)
{
    int id = blockIdx.x * 256 + threadIdx.x;    // 0..65535
    int k = id >> 8, c = id & 255;
#pragma unroll
    for (int t = 0; t < 9; ++t) {
        float v = w1[(size_t)(k * 256 + c) * 9 + t];
        unsigned short hi = bf16_bits(v);
        unsigned short lo = bf16_bits(v - bf16_back(v));
        int region = ((c >> 5) * 9 + t) * 2;
        int base   = region * 8192;
        int pos    = (k >> 4) * 512 + ((c >> 3) & 3) * 128 + (k & 15) * 8 + (c & 7);
        wpk[base + pos]        = hi;
        wpk[base + 8192 + pos] = lo;
    }
}

// ---------------------------------------------------------------------------
// Kernel 0a': transpose w2 (81x256) -> w2t (256x84 fp32, j padded with 0).
// Enables wave-uniform scalar (s_load) weight reads in conv1x1.
// ---------------------------------------------------------------------------
__global__ void pack_w2t(const float* __restrict__ w2, float* __restrict__ w2t)
{
    int j = blockIdx.x;            // 0..83
    int c = threadIdx.x;           // 0..255
    float v = (j < NC1) ? w2[j * 256 + c] : 0.f;
    w2t[c * 84 + j] = v;
}

// ---------------------------------------------------------------------------
// Kernel 0b: pack x into zero-padded pixel-major bf16 hi/lo via LDS transpose.
// ---------------------------------------------------------------------------
__global__ __launch_bounds__(256)
void pack_x(const float* __restrict__ x, unsigned short* __restrict__ xT)
{
    __shared__ float ls[64][257];      // 65,792 B
    const int tid   = threadIdx.x;
    const int chunk = blockIdx.x;      // 0..2 (padded-col chunks of 64)
    const int row   = blockIdx.y;      // 0..101
    const int n     = blockIdx.z;
    const int c0    = chunk * 64;
    const int yy    = row - 1;
    const bool rowok = ((unsigned)yy < (unsigned)Hh);

    const int lanec = tid & 63;        // padded col offset this thread loads
    const int xx    = c0 + lanec - 1;  // source col
    const bool colok = ((unsigned)xx < (unsigned)Ww);
    const bool ok = rowok && colok;

    const size_t rbase = ((size_t)n * Cc) * Pp + (size_t)(rowok ? yy : 0) * Ww
                       + (size_t)(colok ? xx : 0);
#pragma unroll 4
    for (int i = 0; i < 64; ++i) {
        const int c = (tid >> 6) + i * 4;          // wave-strided channels
        float v = 0.f;
        if (ok) v = x[rbase + (size_t)c * Pp];
        ls[lanec][c] = v;
    }
    __syncthreads();

    const int cch = tid;               // channel 0..255
    const int jmax = (c0 + 64 <= PCOLS) ? 64 : (PCOLS - c0);
#pragma unroll 4
    for (int j = 0; j < jmax; ++j) {
        const int pc = c0 + j;
        float v = ls[j][cch];
        unsigned short hi = bf16_bits(v);
        unsigned short lo = bf16_bits(v - bf16_back(v));
        size_t dst = (((size_t)n * PROWS + row) * PCOLS + pc) * 512 + cch;
        xT[dst]       = hi;
        xT[dst + 256] = lo;
    }
}

// ---------------------------------------------------------------------------
// Kernel 1: 3x3 conv (SAME) + bias + ReLU via MFMA bf16x3 split.
// Round-4: intra-tap chunked interleave. Each tap = 4 chunks of 12 MFMA,
// with next-tap loads issued at chunk boundaries, fenced by sched_barrier(0):
//   c0: 4 global A-hi loads (t+1)   | 12 MFMA (t)
//   c1: 4 global A-lo loads (t+1)   | 12 MFMA
//   c2: 4 ds_read B-hi (t+1)        | 12 MFMA
//   c3: 4 ds_read B-lo (t+1)        | 12 MFMA
// Buffer parity = global tap index u&1 (9 odd -> s-loop unrolled x2 so
// parity is compile-time). Per-acc-element MFMA order (hh,hl,lh) preserved
// -> bitwise-identical output. One __syncthreads per s (B dbuf flip).
// ---------------------------------------------------------------------------
#define BBUFB 49152

#define MM(P,M,I,CUR) acc[M][I] = __builtin_amdgcn_mfma_f32_16x16x32_bf16( \
    (P)==2 ? al[CUR][M] : ah[CUR][M], (P)==1 ? bl[CUR][I] : bh[CUR][I], acc[M][I], 0, 0, 0);

#define CH0(C) MM(0,0,0,C) MM(0,0,1,C) MM(0,0,2,C) MM(0,0,3,C) MM(0,1,0,C) MM(0,1,1,C) \
               MM(0,1,2,C) MM(0,1,3,C) MM(0,2,0,C) MM(0,2,1,C) MM(0,2,2,C) MM(0,2,3,C)
#define CH1(C) MM(0,3,0,C) MM(0,3,1,C) MM(0,3,2,C) MM(0,3,3,C) MM(1,0,0,C) MM(1,0,1,C) \
               MM(1,0,2,C) MM(1,0,3,C) MM(1,1,0,C) MM(1,1,1,C) MM(1,1,2,C) MM(1,1,3,C)
#define CH2(C) MM(1,2,0,C) MM(1,2,1,C) MM(1,2,2,C) MM(1,2,3,C) MM(1,3,0,C) MM(1,3,1,C) \
               MM(1,3,2,C) MM(1,3,3,C) MM(2,0,0,C) MM(2,0,1,C) MM(2,0,2,C) MM(2,0,3,C)
#define CH3(C) MM(2,1,0,C) MM(2,1,1,C) MM(2,1,2,C) MM(2,1,3,C) MM(2,2,0,C) MM(2,2,1,C) \
               MM(2,2,2,C) MM(2,2,3,C) MM(2,3,0,C) MM(2,3,1,C) MM(2,3,2,C) MM(2,3,3,C)

#define SBAR __builtin_amdgcn_sched_barrier(0)

#define TAP(S,T,CUR,NX) { \
    const int U_  = (S) * 9 + (T); \
    const int un_ = (U_ + 1 < 72) ? U_ + 1 : 71; \
    loadAh(un_, ah[NX]); \
    SBAR; __builtin_amdgcn_s_setprio(1); CH0(CUR) __builtin_amdgcn_s_setprio(0); SBAR; \
    loadAl(un_, al[NX]); \
    SBAR; __builtin_amdgcn_s_setprio(1); CH1(CUR) __builtin_amdgcn_s_setprio(0); SBAR; \
    if ((T) < 8) readBh((S), (T) + 1, bh[NX]); \
    SBAR; __builtin_amdgcn_s_setprio(1); CH2(CUR) __builtin_amdgcn_s_setprio(0); SBAR; \
    if ((T) < 8) readBl((S), (T) + 1, bl[NX]); \
    SBAR; __builtin_amdgcn_s_setprio(1); CH3(CUR) __builtin_amdgcn_s_setprio(0); SBAR; \
}

#define TAPS_EVEN(S) TAP(S,0,0,1) TAP(S,1,1,0) TAP(S,2,0,1) TAP(S,3,1,0) TAP(S,4,0,1) \
                     TAP(S,5,1,0) TAP(S,6,0,1) TAP(S,7,1,0) TAP(S,8,0,1)
#define TAPS_ODD(S)  TAP(S,0,1,0) TAP(S,1,0,1) TAP(S,2,1,0) TAP(S,3,0,1) TAP(S,4,1,0) \
                     TAP(S,5,0,1) TAP(S,6,1,0) TAP(S,7,0,1) TAP(S,8,1,0)

__global__ __launch_bounds__(512, 2)
void conv3x3_mfma(const unsigned short* __restrict__ xT,
                  const unsigned short* __restrict__ wpk,
                  const float* __restrict__ b1, float* __restrict__ hid)
{
    __shared__ f32x4 ldsbuf[6144];           // 98,304 B = 2 B-buffers
    char* L = (char*)ldsbuf;

    const int tid  = threadIdx.x;
    const int lane = tid & 63;
    const int wv   = tid >> 6;               // 0..7
    const int wm   = wv >> 2;                // 0..1
    const int wn   = wv & 3;                 // 0..3
    const int quad = lane >> 4, lq = lane & 15;

    // bijective XCD swizzle: hwflat in [0,1040), 1040 = 8*130
    const int hwflat  = blockIdx.x + 65 * (blockIdx.y + 2 * blockIdx.z);
    const int logical = (hwflat & 7) * 130 + (hwflat >> 3);
    const int n   = logical / 130;           // XCD j -> batch j
    const int rem = logical - n * 130;
    const int bx  = rem >> 1;                // 0..64
    const int k0b = rem & 1;

    const int rb = bx / 5, cb = bx - rb * 5;
    const int y0 = rb * 8;                   // first output row of tile
    const int x0 = cb * 32;                  // first output col of tile
    const int k0 = k0b * 128;

    const char* xb = (const char*)xT + (size_t)n * XT_BATCH_BYTES;
    // per-lane A base: wpk + m-tile base for this block/wave + lane slot
    const char* abase = (const char*)wpk + (size_t)(k0 >> 4) * 1024
                      + (size_t)(wm * 4) * 1024 + (size_t)lane * 16;

    // staging constants (inverse-swizzled global source, linear LDS dest)
    const unsigned kslot = (lane & 7) ^ (lane >> 3);
    const size_t chnbase = (kslot < 4) ? (size_t)(kslot * 16)
                                       : (size_t)(448 + kslot * 16);

    auto stageB = [&](int s) {
        char* bdst = L + (size_t)(s & 1) * BBUFB;
        const size_t chn = (size_t)s * 64 + chnbase;
#pragma unroll
        for (int k6 = 0; k6 < 6; ++k6) {
            const int j   = wv + 8 * k6;                 // 0..47
            const int pix = 8 * j + (lane >> 3);         // 0..383
            const int r   = pix / 34;
            const int c   = pix - r * 34;
            int prow = y0 + r; prow = prow < 102 ? prow : 101;
            const char* g = xb + (((size_t)(prow * 154 + x0 + c)) << 10) + chn;
            gload_lds16(g, bdst + (size_t)j * 1024);
        }
    };

    auto loadAh = [&](int u, bf16x8 (&a)[4]) {
        const char* p0 = abase + (size_t)u * 32768;
#pragma unroll
        for (int m = 0; m < 4; ++m) a[m] = *(const bf16x8*)(p0 + m * 1024);
    };
    auto loadAl = [&](int u, bf16x8 (&a)[4]) {
        const char* p0 = abase + (size_t)u * 32768 + 16384;
#pragma unroll
        for (int m = 0; m < 4; ++m) a[m] = *(const bf16x8*)(p0 + m * 1024);
    };

    const int pix0 = wn * 2 * 34 + lq;
    auto readBh = [&](int s, int t, bf16x8 (&b)[4]) {
        const char* Bb = L + (size_t)(s & 1) * BBUFB;
        const int ty = t / 3, tx = t - ty * 3;
        const int pb0 = pix0 + ty * 34 + tx;
#pragma unroll
        for (int i = 0; i < 4; ++i) {
            const int pix = pb0 + (i >> 1) * 34 + (i & 1) * 16;
            const int a = pix * 128 + ((quad ^ (pix & 7)) << 4);
            b[i] = *(const bf16x8*)(Bb + a);
        }
    };
    auto readBl = [&](int s, int t, bf16x8 (&b)[4]) {
        const char* Bb = L + (size_t)(s & 1) * BBUFB;
        const int ty = t / 3, tx = t - ty * 3;
        const int pb0 = pix0 + ty * 34 + tx;
#pragma unroll
        for (int i = 0; i < 4; ++i) {
            const int pix = pb0 + (i >> 1) * 34 + (i & 1) * 16;
            const int a = (pix * 128 + ((quad ^ (pix & 7)) << 4)) ^ 64;
            b[i] = *(const bf16x8*)(Bb + a);
        }
    };

    f32x4 acc[4][4];
#pragma unroll
    for (int a = 0; a < 4; ++a)
#pragma unroll
        for (int b = 0; b < 4; ++b) acc[a][b] = 0;

    bf16x8 ah[2][4], al[2][4], bh[2][4], bl[2][4];

    // prologue: stage B(0); prime frags for (s=0, t=0) into parity-0 set
    stageB(0);
    __syncthreads();
    loadAh(0, ah[0]); loadAl(0, al[0]);
    readBh(0, 0, bh[0]); readBl(0, 0, bl[0]);

#pragma unroll 1
    for (int sp = 0; sp < 4; ++sp) {
        const int s0 = sp * 2, s1 = s0 + 1;
        stageB(s0 + 1);                        // writes buf (s0+1)&1 = 1
        TAPS_EVEN(s0)
        __syncthreads();                       // drains stage; buf 1 ready
        readBh(s1, 0, bh[1]); readBl(s1, 0, bl[1]);
        if (s1 < 7) stageB(s1 + 1);            // writes buf 0
        TAPS_ODD(s1)
        __syncthreads();
        if (s1 < 7) { readBh(s1 + 1, 0, bh[0]); readBl(s1 + 1, 0, bl[0]); }
    }

    // epilogue: bias + relu; D row = quad*4 + reg
#pragma unroll
    for (int m = 0; m < 4; ++m) {
        const int kb = k0 + wm * 64 + m * 16 + quad * 4;
        const float b0 = b1[kb], b1v = b1[kb + 1], b2v = b1[kb + 2], b3v = b1[kb + 3];
#pragma unroll
        for (int i = 0; i < 4; ++i) {
            const int y = y0 + wn * 2 + (i >> 1);
            const int xcol = x0 + (i & 1) * 16 + lq;
            if (y < Hh && xcol < Ww) {
                float* hp = hid + ((size_t)n * Cc + kb) * Pp + y * Ww + xcol;
                hp[0]              = fmaxf(acc[m][i].x + b0,  0.f);
                hp[Pp]             = fmaxf(acc[m][i].y + b1v, 0.f);
                hp[2 * Pp]         = fmaxf(acc[m][i].z + b2v, 0.f);
                hp[3 * (size_t)Pp] = fmaxf(acc[m][i].w + b3v, 0.f);
            }
        }
    }
}

// ---------------------------------------------------------------------------
// Kernel 2: 1x1 conv to 81 logits + bias, softmax over 81, argmax over 80.
// Round-4 rewrite: weights via the SCALAR path. w2t[c][84] rows are
// wave-uniform -> s_load into SGPRs, v_fmac v,s,v. Eliminates ALL LDS
// traffic (old version was LDS-throughput-bound: 21.5 KB ds_read per thread
// per chunk). Same j-then-c summation order -> bitwise-identical logits.
// ---------------------------------------------------------------------------
__global__ __launch_bounds__(256, 2)
void conv1x1_softmax(const float* __restrict__ hid, const float* __restrict__ w2t,
                     const float* __restrict__ b2, float* __restrict__ logits,
                     float* __restrict__ pmap, int* __restrict__ cmap)
{
    const int tid = threadIdx.x;
    const int p   = blockIdx.x * 256 + tid;
    const int n   = blockIdx.y;
    const bool valid = (p < Pp);
    const int psafe = valid ? p : 0;

    float acc[84];
#pragma unroll
    for (int j = 0; j < 84; ++j) acc[j] = 0.f;

    const float* hptr = hid + ((size_t)n * Cc) * Pp + psafe;

    // depth-2 h prefetch; weight rows ride the scalar cache
    float h0 = hptr[0];
    float h1 = hptr[(size_t)Pp];
#pragma unroll 1
    for (int c = 0; c < Cc; ++c) {
        const int cn = (c + 2 < Cc) ? c + 2 : Cc - 1;
        const float hn = hptr[(size_t)cn * Pp];
        const float* wr = w2t + c * 84;        // uniform address -> s_load
#pragma unroll
        for (int j = 0; j < 84; ++j) acc[j] = fmaf(wr[j], h0, acc[j]);
        h0 = h1; h1 = hn;
    }

    if (valid) {
#pragma unroll
        for (int j = 0; j < NC1; ++j) acc[j] += b2[j];

        float* lp = logits + (size_t)n * NC1 * Pp + p;
#pragma unroll
        for (int j = 0; j < NC1; ++j) lp[(size_t)j * Pp] = acc[j];

        float m = -3.4e38f;
#pragma unroll
        for (int j = 0; j < NC1; ++j) m = fmaxf(m, acc[j]);
        float s = 0.f;
#pragma unroll
        for (int j = 0; j < NC1; ++j) s += __expf(acc[j] - m);
        float best = -3.4e38f; int bi = 0;
#pragma unroll
        for (int j = 0; j < NCLS; ++j) {   // first occurrence wins (strict >)
            if (acc[j] > best) { best = acc[j]; bi = j; }
        }
        pmap[n * Pp + p] = __expf(best - m) / s;
        cmap[n * Pp + p] = bi;
    }
}

// ---------------------------------------------------------------------------
// Kernel 3: score = p + 1{local max}.
// ---------------------------------------------------------------------------
__global__ void local_score(const float* __restrict__ pmap, const int* __restrict__ cmap,
                            float* __restrict__ scores)
{
    int p = blockIdx.x * 256 + threadIdx.x;
    int n = blockIdx.y;
    if (p >= Pp) return;
    int base = n * Pp;
    float pv = pmap[base + p];
    int   c  = cmap[base + p];
    int y = p / Ww, xc = p - y * Ww;
    bool ok = (pv >= 1e-6f);
#pragma unroll
    for (int dy = -1; dy <= 1; ++dy)
#pragma unroll
        for (int dx = -1; dx <= 1; ++dx) {
            if (dy == 0 && dx == 0) continue;
            int yy = y + dy, xx = xc + dx;
            if (yy >= 0 && yy < Hh && xx >= 0 && xx < Ww) {
                int q = base + yy * Ww + xx;
                if (cmap[q] == c && pmap[q] > pv) ok = false;
            }
        }
    scores[base + p] = pv + (ok ? 1.f : 0.f);
}

// ---------------------------------------------------------------------------
// Kernel 4: per-batch top-100 (value desc, index asc on ties) + gathers.
// ---------------------------------------------------------------------------
__global__ __launch_bounds__(1024)
void topk_gather(const float* __restrict__ scores, const float* __restrict__ x,
                 const float* __restrict__ pos, float* __restrict__ oprop,
                 float* __restrict__ opos)
{
    __shared__ float sv[Pp];                 // 60.8 KB
    __shared__ int sidx[KTOP];
    __shared__ unsigned long long red[16];
    __shared__ unsigned long long bcast;
    const int tid = threadIdx.x;
    const int n   = blockIdx.x;

    for (int i = tid; i < Pp; i += 1024) sv[i] = scores[n * Pp + i];
    __syncthreads();

    auto scan = [&]() -> unsigned long long {
        unsigned long long best = 0ull;
#pragma unroll
        for (int k = 0; k < 15; ++k) {       // 15*1024 = 15360 >= 15200
            const int i = tid + k * 1024;
            if (i < Pp) {
                unsigned fb = __float_as_uint(sv[i]);   // scores>0 => monotone
                unsigned long long key =
                    ((unsigned long long)fb << 32) | (unsigned)(0xFFFF - i);
                best = key > best ? key : best;
            }
        }
        return best;
    };

    unsigned long long mybest = scan();

    for (int it = 0; it < KTOP; ++it) {
        unsigned long long b = mybest;
#pragma unroll
        for (int off = 32; off > 0; off >>= 1) {
            unsigned long long o = __shfl_down(b, off, 64);
            b = o > b ? o : b;
        }
        if ((tid & 63) == 0) red[tid >> 6] = b;
        __syncthreads();
        if (tid == 0) {
            unsigned long long bf = red[0];
#pragma unroll
            for (int w = 1; w < 16; ++w) bf = red[w] > bf ? red[w] : bf;
            int idx = 0xFFFF - (int)(bf & 0xFFFFFFFFull);
            sidx[it] = idx;
            sv[idx]  = 0.f;                  // remove winner
            bcast    = bf;
        }
        __syncthreads();
        const unsigned long long w = bcast;
        const int idx = 0xFFFF - (int)(w & 0xFFFFFFFFull);
        if ((idx & 1023) == tid) mybest = scan();   // only owner rescans
    }

    for (int t = tid; t < Cc * KTOP; t += 1024) {
        int c = t / KTOP;
        int i = t - c * KTOP;
        int idx = sidx[i];
        oprop[n * Cc * KTOP + c * KTOP + i] = x[((size_t)n * Cc + c) * Pp + idx];
        opos [n * Cc * KTOP + c * KTOP + i] = pos[(size_t)c * Pp + idx];
    }
}

// ---------------------------------------------------------------------------
extern "C" void kernel_launch(void* const* d_in, const int* in_sizes, int n_in,
                              void* d_out, int out_size, void* d_ws, size_t ws_size,
                              hipStream_t stream)
{
    const float* x   = (const float*)d_in[0];
    const float* pos = (const float*)d_in[1];
    const float* w1  = (const float*)d_in[2];
    const float* b1  = (const float*)d_in[3];
    const float* w2  = (const float*)d_in[4];
    const float* b2  = (const float*)d_in[5];

    float* out    = (float*)d_out;
    float* oprop  = out;                                         // (8,256,100)
    float* oposE  = out + (size_t)NBATCH * Cc * KTOP;            // (8,256,100)
    float* logits = out + (size_t)2 * NBATCH * Cc * KTOP;        // (8,81,100,152)

    // wpk (2.36 MB, bf16 fragment-ordered w1) borrows the logits region:
    // written by pack_w, consumed by conv3x3_mfma, overwritten by conv1x1.
    unsigned short* wpk = (unsigned short*)logits;

    // workspace: hid | xTpad | pmap | cmap | scores | w2t
    float* ws  = (float*)d_ws;
    float* hid = ws;                                             // 8*256*15200 f32
    unsigned short* xT = (unsigned short*)(ws + (size_t)NBATCH * Cc * Pp);
    char* after_xt = (char*)xT + (size_t)NBATCH * XT_BATCH_BYTES;
    float* pmap   = (float*)after_xt;                            // 8*15200
    int*   cmap   = (int*)(pmap + (size_t)NBATCH * Pp);          // 8*15200
    float* scores = (float*)(cmap + (size_t)NBATCH * Pp);        // 8*15200
    float* w2t    = scores + (size_t)NBATCH * Pp;                // 256*84 f32

    pack_w<<<256, 256, 0, stream>>>(w1, wpk);
    pack_w2t<<<84, 256, 0, stream>>>(w2, w2t);
    pack_x<<<dim3(3, PROWS, NBATCH), 256, 0, stream>>>(x, xT);
    // 13 row-blocks (8 rows) x 5 col-blocks (32 cols) = 65 pixel tiles
    conv3x3_mfma<<<dim3(65, 2, NBATCH), 512, 0, stream>>>(
        xT, wpk, b1, hid);
    conv1x1_softmax<<<dim3((Pp + 255) / 256, NBATCH), 256, 0, stream>>>(
        hid, w2t, b2, logits, pmap, cmap);
    local_score<<<dim3((Pp + 255) / 256, NBATCH), 256, 0, stream>>>(
        pmap, cmap, scores);
    topk_gather<<<NBATCH, 1024, 0, stream>>>(scores, x, pos, oprop, oposE);
}